// Round 1
// baseline (183.441 us; speedup 1.0000x reference)
//
#include <hip/hip_runtime.h>

// Variance loss: pred [512,240,240] f32, gt [240,240] f32 -> scalar f32.
// One-pass sum / sum-of-squares per 20x20 patch (12x12 grid), double accum.
// var = E[x^2] - 2*m*E[x] + m^2 with m = global pred mean (used for BOTH).

#define NB 128            // pred blocks per g1 band: 512 batches / 4 per block

__global__ __launch_bounds__(256) void vl_stage1(
    const float* __restrict__ pred, const float* __restrict__ gt,
    double* __restrict__ predS, double* __restrict__ predSS,
    double* __restrict__ gtS, double* __restrict__ gtSS)
{
    const int g1 = blockIdx.x;        // patch row band 0..11
    const int j  = blockIdx.y;        // 0..NB-1 pred chunk, NB = gt
    const int t  = threadIdx.x;       // 256 threads, 240 active for loads
    const int rg = t / 60;            // row-in-group 0..3
    const int cg = t % 60;            // float4 column group 0..59
    const bool active = (t < 240);

    double s = 0.0, s0 = 0.0, s1 = 0.0, s2 = 0.0, s3 = 0.0;

    if (j < NB) {
        // 4 batches, rows g1*20 .. g1*20+19, all 240 cols.
        const float* base = pred + (size_t)(j * 4) * 57600 + g1 * 4800
                            + rg * 240 + cg * 4;
        if (active) {
            #pragma unroll
            for (int q = 0; q < 4; ++q) {
                const float* bb = base + (size_t)q * 57600;
                #pragma unroll
                for (int grp = 0; grp < 5; ++grp) {
                    float4 v = *(const float4*)(bb + grp * 960);
                    double x = v.x, y = v.y, z = v.z, w = v.w;
                    s += (x + y) + (z + w);
                    s0 = fma(x, x, s0);
                    s1 = fma(y, y, s1);
                    s2 = fma(z, z, s2);
                    s3 = fma(w, w, s3);
                }
            }
        }
    } else {
        const float* bb = gt + g1 * 4800 + rg * 240 + cg * 4;
        if (active) {
            #pragma unroll
            for (int grp = 0; grp < 5; ++grp) {
                float4 v = *(const float4*)(bb + grp * 960);
                double x = v.x, y = v.y, z = v.z, w = v.w;
                s += (x + y) + (z + w);
                s0 = fma(x, x, s0);
                s1 = fma(y, y, s1);
                s2 = fma(z, z, s2);
                s3 = fma(w, w, s3);
            }
        }
    }
    double ss = (s0 + s1) + (s2 + s3);

    __shared__ double shs[256];
    __shared__ double shss[256];
    shs[t] = s;
    shss[t] = ss;
    __syncthreads();

    // 12 bins (patch columns g2); bin of thread = (t%60)/5.
    if (t < 12) {
        double as = 0.0, ass = 0.0;
        #pragma unroll
        for (int r = 0; r < 4; ++r) {
            #pragma unroll
            for (int k = 0; k < 5; ++k) {
                int idx = r * 60 + t * 5 + k;
                as  += shs[idx];
                ass += shss[idx];
            }
        }
        if (j < NB) {
            size_t o = ((size_t)g1 * NB + j) * 12 + t;
            predS[o]  = as;
            predSS[o] = ass;
        } else {
            gtS[g1 * 12 + t]  = as;
            gtSS[g1 * 12 + t] = ass;
        }
    }
}

__global__ __launch_bounds__(256) void vl_stage2(
    const double* __restrict__ predS, const double* __restrict__ predSS,
    const double* __restrict__ gtS, const double* __restrict__ gtSS,
    float* __restrict__ out)
{
    const int t = threadIdx.x;
    __shared__ double S[144], SS[144];
    __shared__ double red[256];

    double a = 0.0, b = 0.0;
    if (t < 144) {
        const int g1 = t / 12, g2 = t % 12;
        for (int nb = 0; nb < NB; ++nb) {
            size_t o = ((size_t)g1 * NB + nb) * 12 + g2;
            a += predS[o];
            b += predSS[o];
        }
        S[t]  = a;
        SS[t] = b;
    }
    red[t] = (t < 144) ? a : 0.0;
    __syncthreads();
    for (int off = 128; off > 0; off >>= 1) {
        if (t < off) red[t] += red[t + off];
        __syncthreads();
    }
    const double m = red[0] * (1.0 / (512.0 * 240.0 * 240.0));
    __syncthreads();   // everyone read red[0] before we overwrite

    double dsq = 0.0;
    if (t < 144) {
        const double inv_n1 = 1.0 / (512.0 * 400.0);
        const double inv_n2 = 1.0 / 400.0;
        double pv = fma(-2.0 * m, S[t] * inv_n1, SS[t] * inv_n1) + m * m;
        double gv = fma(-2.0 * m, gtS[t] * inv_n2, gtSS[t] * inv_n2) + m * m;
        double d = pv - gv;
        dsq = d * d;
    }
    red[t] = dsq;
    __syncthreads();
    for (int off = 128; off > 0; off >>= 1) {
        if (t < off) red[t] += red[t + off];
        __syncthreads();
    }
    if (t == 0) out[0] = (float)(red[0] * (0.5 / 12.0));
}

extern "C" void kernel_launch(void* const* d_in, const int* in_sizes, int n_in,
                              void* d_out, int out_size, void* d_ws, size_t ws_size,
                              hipStream_t stream) {
    const float* pred = (const float*)d_in[0];   // [512,240,240]
    const float* gt   = (const float*)d_in[1];   // [240,240]
    float* out = (float*)d_out;

    double* ws = (double*)d_ws;
    double* predS  = ws;                         // 12*NB*12 = 18432 doubles
    double* predSS = predS + 12 * NB * 12;       // 18432 doubles
    double* gtS    = predSS + 12 * NB * 12;      // 144 doubles
    double* gtSS   = gtS + 144;                  // 144 doubles
    // total ws: ~295 KB

    vl_stage1<<<dim3(12, NB + 1), 256, 0, stream>>>(pred, gt, predS, predSS,
                                                    gtS, gtSS);
    vl_stage2<<<1, 256, 0, stream>>>(predS, predSS, gtS, gtSS, out);
}

// Round 3
// 169.430 us; speedup vs baseline: 1.0827x; 1.0827x over previous
//
#include <hip/hip_runtime.h>

// Variance loss: pred [512,240,240] f32, gt [240,240] f32 -> scalar f32.
// One-pass sum / sum-of-squares per 20x20 patch (12x12 grid), double accum.
// var = E[x^2] - 2*m*E[x] + m^2 with m = global pred mean (used for BOTH).
//
// Partials layout: predS[(g1*12+g2)*NB + j]  -> stage2 thread (g1,g2) reads
// 128 CONTIGUOUS doubles (double2-vectorizable, deep MLP), fixing the
// latency-bound single-block reduction suspected in round 1.

#define NB 128            // pred chunks per g1 band: 512 batches / 4 per block

typedef float  vfloat4 __attribute__((ext_vector_type(4)));  // native vec for
                                                             // nontemporal ld

__global__ __launch_bounds__(256) void vl_stage1(
    const float* __restrict__ pred, const float* __restrict__ gt,
    double* __restrict__ predS, double* __restrict__ predSS,
    double* __restrict__ gtS, double* __restrict__ gtSS)
{
    const int g1 = blockIdx.x;        // patch row band 0..11
    const int j  = blockIdx.y;        // 0..NB-1 pred chunk; j==NB -> gt
    const int t  = threadIdx.x;       // 256 threads, 240 active for loads
    const int rg = t / 60;            // row-in-group 0..3
    const int cg = t % 60;            // float4 column group 0..59
    const bool active = (t < 240);

    double s = 0.0, s0 = 0.0, s1 = 0.0, s2 = 0.0, s3 = 0.0;

    if (j < NB) {
        // 4 batches, rows g1*20 .. g1*20+19, all 240 cols.
        const float* base = pred + (size_t)(j * 4) * 57600 + g1 * 4800
                            + rg * 240 + cg * 4;
        if (active) {
            #pragma unroll
            for (int q = 0; q < 4; ++q) {
                const float* bb = base + (size_t)q * 57600;
                #pragma unroll
                for (int grp = 0; grp < 5; ++grp) {
                    vfloat4 v = __builtin_nontemporal_load(
                        (const vfloat4*)(bb + grp * 960));
                    double x = v.x, y = v.y, z = v.z, w = v.w;
                    s += (x + y) + (z + w);
                    s0 = fma(x, x, s0);
                    s1 = fma(y, y, s1);
                    s2 = fma(z, z, s2);
                    s3 = fma(w, w, s3);
                }
            }
        }
    } else {
        const float* bb = gt + g1 * 4800 + rg * 240 + cg * 4;
        if (active) {
            #pragma unroll
            for (int grp = 0; grp < 5; ++grp) {
                vfloat4 v = *(const vfloat4*)(bb + grp * 960);
                double x = v.x, y = v.y, z = v.z, w = v.w;
                s += (x + y) + (z + w);
                s0 = fma(x, x, s0);
                s1 = fma(y, y, s1);
                s2 = fma(z, z, s2);
                s3 = fma(w, w, s3);
            }
        }
    }
    double ss = (s0 + s1) + (s2 + s3);

    __shared__ double shs[256];
    __shared__ double shss[256];
    shs[t] = s;
    shss[t] = ss;
    __syncthreads();

    // 12 bins (patch columns g2); bin of thread = (t%60)/5.
    if (t < 12) {
        double as = 0.0, ass = 0.0;
        #pragma unroll
        for (int r = 0; r < 4; ++r) {
            #pragma unroll
            for (int k = 0; k < 5; ++k) {
                int idx = r * 60 + t * 5 + k;
                as  += shs[idx];
                ass += shss[idx];
            }
        }
        if (j < NB) {
            size_t o = (size_t)(g1 * 12 + t) * NB + j;   // [patch][chunk]
            predS[o]  = as;
            predSS[o] = ass;
        } else {
            gtS[g1 * 12 + t]  = as;
            gtSS[g1 * 12 + t] = ass;
        }
    }
}

__global__ __launch_bounds__(256) void vl_stage2(
    const double* __restrict__ predS, const double* __restrict__ predSS,
    const double* __restrict__ gtS, const double* __restrict__ gtSS,
    float* __restrict__ out)
{
    const int t = threadIdx.x;
    __shared__ double S[144], SS[144];
    __shared__ double red[256];

    double a = 0.0, b = 0.0;
    if (t < 144) {
        // 128 contiguous doubles per array: double2 loads, unrolled for MLP.
        const double2* pa = (const double2*)(predS  + (size_t)t * NB);
        const double2* pb = (const double2*)(predSS + (size_t)t * NB);
        #pragma unroll 8
        for (int k = 0; k < NB / 2; ++k) {
            double2 va = pa[k];
            double2 vb = pb[k];
            a += va.x + va.y;
            b += vb.x + vb.y;
        }
        S[t]  = a;
        SS[t] = b;
    }
    red[t] = (t < 144) ? a : 0.0;
    __syncthreads();
    for (int off = 128; off > 0; off >>= 1) {
        if (t < off) red[t] += red[t + off];
        __syncthreads();
    }
    const double m = red[0] * (1.0 / (512.0 * 240.0 * 240.0));
    __syncthreads();   // everyone read red[0] before we overwrite

    double dsq = 0.0;
    if (t < 144) {
        const double inv_n1 = 1.0 / (512.0 * 400.0);
        const double inv_n2 = 1.0 / 400.0;
        double pv = fma(-2.0 * m, S[t] * inv_n1, SS[t] * inv_n1) + m * m;
        double gv = fma(-2.0 * m, gtS[t] * inv_n2, gtSS[t] * inv_n2) + m * m;
        double d = pv - gv;
        dsq = d * d;
    }
    red[t] = dsq;
    __syncthreads();
    for (int off = 128; off > 0; off >>= 1) {
        if (t < off) red[t] += red[t + off];
        __syncthreads();
    }
    if (t == 0) out[0] = (float)(red[0] * (0.5 / 12.0));
}

extern "C" void kernel_launch(void* const* d_in, const int* in_sizes, int n_in,
                              void* d_out, int out_size, void* d_ws, size_t ws_size,
                              hipStream_t stream) {
    const float* pred = (const float*)d_in[0];   // [512,240,240]
    const float* gt   = (const float*)d_in[1];   // [240,240]
    float* out = (float*)d_out;

    double* ws = (double*)d_ws;
    double* predS  = ws;                         // 144*NB = 18432 doubles
    double* predSS = predS + 144 * NB;           // 18432 doubles
    double* gtS    = predSS + 144 * NB;          // 144 doubles
    double* gtSS   = gtS + 144;                  // 144 doubles
    // total ws: ~295 KB

    vl_stage1<<<dim3(12, NB + 1), 256, 0, stream>>>(pred, gt, predS, predSS,
                                                    gtS, gtSS);
    vl_stage2<<<1, 256, 0, stream>>>(predS, predSS, gtS, gtSS, out);
}